// Round 4
// baseline (54.895 us; speedup 1.0000x reference)
//
#include <hip/hip_runtime.h>

// Policy MLP via split-precision bf16 MFMA (round 4).
// B=131072, D=32, L=40 hidden + final 32->1 (pseudo-layer 41).
//
// Round-4 changes vs round 3:
//  * __launch_bounds__(256, 1): relax the compiler's occupancy-driven VGPR
//    budget (round-3 VGPR_Count=44 << live state => acc/frags lived in AGPRs,
//    costing ~150 v_accvgpr/copy VALU instr per layer).
//  * 2 batch tiles per wave (64 rows): per-layer weight fragments are loaded
//    once and feed two independent MFMA chains -> weight VMEM halved, 2-way
//    ILP hides MFMA latency at 2 waves/SIMD.
// k-axis permutation pi(kk,h,w,e) = 16kk + 8(w>>1) + 4h + 2(w&1) + e applied
// to both A (tables) and B (activations) makes D's natural reg layout equal
// the next layer's B layout: no cross-lane ops anywhere.
// Terms: W_hi*x_hi + W_lo*x_hi + W_hi*x_lo + bias-MFMA (lo*lo dropped).

#define NB 131072
#define DD 32
#define NL 40
#define WTAB_BYTES ((NL + 1) * 4 * 64 * 16)

typedef short bf16x8 __attribute__((ext_vector_type(8)));
typedef float f32x16 __attribute__((ext_vector_type(16)));

union Frag { int4 q; int i[4]; bf16x8 v; };

__device__ inline unsigned f2bf(float f) {  // fp32 -> bf16 bits, RNE
  unsigned u = __float_as_uint(f);
  return (u + 0x7fffu + ((u >> 16) & 1u)) >> 16;
}
__device__ inline float bf2f(unsigned s) { return __int_as_float((int)(s << 16)); }

// ---- table build: W/bias into pi-permuted MFMA A-fragment order ----------
__global__ __launch_bounds__(64) void build_tables(
    const float* __restrict__ Wh, const float* __restrict__ bh,
    const float* __restrict__ Wout, const float* __restrict__ bout,
    int4* __restrict__ wtab, int* __restrict__ btab) {
  const int l = blockIdx.x;      // 0..40 (40 == output layer)
  const int lane = threadIdx.x;  // 0..63
  const int m = lane & 31, h = lane >> 5;
  for (int g = 0; g < 4; ++g) {  // {hi,lo} x {kk}
    const int kk = g & 1;
    const bool lopart = (g >= 2);
    int wds[4];
    for (int w = 0; w < 4; ++w) {
      const int k = 16 * kk + 8 * (w >> 1) + 4 * h + 2 * (w & 1);  // pi(...)
      float a, b;
      if (l < NL) {
        a = Wh[(l * 32 + m) * 32 + k];
        b = Wh[(l * 32 + m) * 32 + k + 1];
      } else {  // final layer: row 0 = W_out, rest zero
        a = (m == 0) ? Wout[k] : 0.f;
        b = (m == 0) ? Wout[k + 1] : 0.f;
      }
      unsigned ah = f2bf(a), bhh = f2bf(b);
      unsigned al = f2bf(a - bf2f(ah)), bl = f2bf(b - bf2f(bhh));
      wds[w] = lopart ? (int)(al | (bl << 16)) : (int)(ah | (bhh << 16));
    }
    wtab[(l * 4 + g) * 64 + lane] = make_int4(wds[0], wds[1], wds[2], wds[3]);
  }
  // bias MFMA A-operand: bias_hi at k-pos 0, bias_lo at k-pos 1 (h==0 lanes)
  float bv = (l < NL) ? bh[l * 32 + m] : ((m == 0) ? bout[0] : 0.f);
  unsigned bhi = f2bf(bv);
  unsigned blo = f2bf(bv - bf2f(bhi));
  btab[l * 64 + lane] = (h == 0) ? (int)(bhi | (blo << 16)) : 0;
}

// ---- main kernel ----------------------------------------------------------
__device__ inline int cvt_pk(float a, float b) {  // a -> lo16, b -> hi16
  int r;
  asm("v_cvt_pk_bf16_f32 %0, %1, %2" : "=v"(r) : "v"(a), "v"(b));
  return r;
}
__device__ inline void split2(float a, float b, int& hi, int& lo) {
  hi = cvt_pk(a, b);
  float ha = __int_as_float(hi << 16);
  float hb = __int_as_float(hi & (int)0xffff0000u);
  lo = cvt_pk(a - ha, b - hb);
}

#define MFMA(A, B, C) __builtin_amdgcn_mfma_f32_32x32x16_bf16((A), (B), (C), 0, 0, 0)

__global__ __launch_bounds__(256, 1) void policy_mfma(
    const float* __restrict__ state, const int4* __restrict__ wtab,
    const int* __restrict__ btab, float* __restrict__ out) {
  const int lane = threadIdx.x & 63;
  const int wid = (int)((blockIdx.x * blockDim.x + threadIdx.x) >> 6);
  const int n = lane & 31, h = lane >> 5;
  const int bbase = wid * 64;  // two 32-row tiles per wave

  // Layer-0 B-operand (X^T) frags for both tiles, pi-permuted layout:
  // position (kk, h, w=0,1) <- x[16kk+4h+0..3]; (w=2,3) <- x[16kk+8+4h+0..3]
  Frag bhi0[2], bhi1[2], blo0[2], blo1[2];
#pragma unroll
  for (int t = 0; t < 2; ++t) {
    const float* xr = state + (size_t)(bbase + 32 * t + n) * DD;
    float4 xa = *(const float4*)(xr + 4 * h);
    float4 xb = *(const float4*)(xr + 8 + 4 * h);
    float4 xc = *(const float4*)(xr + 16 + 4 * h);
    float4 xd = *(const float4*)(xr + 24 + 4 * h);
    split2(xa.x, xa.y, bhi0[t].i[0], blo0[t].i[0]);
    split2(xa.z, xa.w, bhi0[t].i[1], blo0[t].i[1]);
    split2(xb.x, xb.y, bhi0[t].i[2], blo0[t].i[2]);
    split2(xb.z, xb.w, bhi0[t].i[3], blo0[t].i[3]);
    split2(xc.x, xc.y, bhi1[t].i[0], blo1[t].i[0]);
    split2(xc.z, xc.w, bhi1[t].i[1], blo1[t].i[1]);
    split2(xd.x, xd.y, bhi1[t].i[2], blo1[t].i[2]);
    split2(xd.z, xd.w, bhi1[t].i[3], blo1[t].i[3]);
  }

  Frag bones;  // bias-MFMA B: k-pos 0,1 = 1.0 (h==0 lanes)
  bones.i[0] = (h == 0) ? 0x3F803F80 : 0;
  bones.i[1] = bones.i[2] = bones.i[3] = 0;

  Frag ab;  // bias A frag (dword 0 per-layer, rest zero)
  ab.i[1] = ab.i[2] = ab.i[3] = 0;

  const f32x16 zero16 = {0, 0, 0, 0, 0, 0, 0, 0, 0, 0, 0, 0, 0, 0, 0, 0};

  // prefetch layer-0 fragments (uniform pointer stride -> SGPR adds)
  const int4* wp = wtab + lane;
  const int* bp = btab + lane;
  int4 nw0 = wp[0], nw1 = wp[64], nw2 = wp[128], nw3 = wp[192];
  int nb = bp[0];

  float result[2] = {0.f, 0.f};

#pragma unroll 1
  for (int l = 0; l <= NL; ++l) {
    Frag wh0, wh1, wl0, wl1;
    wh0.q = nw0; wh1.q = nw1; wl0.q = nw2; wl1.q = nw3;
    ab.i[0] = nb;
    if (l < NL) {  // prefetch next layer
      wp += 256; bp += 64;
      nw0 = wp[0]; nw1 = wp[64]; nw2 = wp[128]; nw3 = wp[192];
      nb = bp[0];
    }

    // two independent 7-MFMA chains, interleaved for latency hiding
    f32x16 a0 = MFMA(ab.v, bones.v, zero16);
    f32x16 a1 = MFMA(ab.v, bones.v, zero16);
    a0 = MFMA(wh0.v, bhi0[0].v, a0);
    a1 = MFMA(wh0.v, bhi0[1].v, a1);
    a0 = MFMA(wl0.v, bhi0[0].v, a0);
    a1 = MFMA(wl0.v, bhi0[1].v, a1);
    a0 = MFMA(wh1.v, bhi1[0].v, a0);
    a1 = MFMA(wh1.v, bhi1[1].v, a1);
    a0 = MFMA(wl1.v, bhi1[0].v, a0);
    a1 = MFMA(wl1.v, bhi1[1].v, a1);
    a0 = MFMA(wh0.v, blo0[0].v, a0);
    a1 = MFMA(wh0.v, blo0[1].v, a1);
    a0 = MFMA(wh1.v, blo1[0].v, a0);
    a1 = MFMA(wh1.v, blo1[1].v, a1);

    if (l < NL) {
      // relu + hi/lo split; reg-pair p feeds B position (kk=p>>2, w=p&3)
#pragma unroll
      for (int p = 0; p < 8; ++p) {
        float xa0 = fmaxf(a0[2 * p], 0.f), ya0 = fmaxf(a0[2 * p + 1], 0.f);
        float xa1 = fmaxf(a1[2 * p], 0.f), ya1 = fmaxf(a1[2 * p + 1], 0.f);
        int hi, lo;
        split2(xa0, ya0, hi, lo);
        if (p < 4) { bhi0[0].i[p] = hi; blo0[0].i[p] = lo; }
        else       { bhi1[0].i[p - 4] = hi; blo1[0].i[p - 4] = lo; }
        split2(xa1, ya1, hi, lo);
        if (p < 4) { bhi0[1].i[p] = hi; blo0[1].i[p] = lo; }
        else       { bhi1[1].i[p - 4] = hi; blo1[1].i[p - 4] = lo; }
      }
    } else {
      result[0] = a0[0];  // D row 0 (h==0 lanes), col n = batch
      result[1] = a1[0];
    }
  }

  if (h == 0) {
    out[bbase + n] = result[0];
    out[bbase + 32 + n] = result[1];
  }
}

extern "C" void kernel_launch(void* const* d_in, const int* in_sizes, int n_in,
                              void* d_out, int out_size, void* d_ws, size_t ws_size,
                              hipStream_t stream) {
  const float* state = (const float*)d_in[0];
  const float* Wh    = (const float*)d_in[1];
  const float* bh    = (const float*)d_in[2];
  const float* Wout  = (const float*)d_in[3];
  const float* bout  = (const float*)d_in[4];
  float* out = (float*)d_out;

  int4* wtab = (int4*)d_ws;
  int* btab  = (int*)((char*)d_ws + WTAB_BYTES);

  build_tables<<<NL + 1, 64, 0, stream>>>(Wh, bh, Wout, bout, wtab, btab);

  // 131072 rows / 64 per wave = 2048 waves; 256-thread blocks -> 512 blocks.
  policy_mfma<<<(NB / 64) * 64 / 256, 256, 0, stream>>>(state, wtab, btab, out);
}

// Round 5
// 53.677 us; speedup vs baseline: 1.0227x; 1.0227x over previous
//
#include <hip/hip_runtime.h>

// Policy MLP via split-precision bf16 MFMA (round 5: 16x16x32 ILP redesign).
// B=131072, D=32, L=40 hidden + final 32->1 (pseudo-layer 41).
//
// Per wave: 32 batch cols x 32 out rows as FOUR independent 16x16 accs, each
// a 3-deep mfma_f32_16x16x32_bf16 chain (K=32 in one instr):
//   acc = Whi*xhi (C = fp32 bias from table) ; += Wlo*xhi ; += Whi*xlo
// Bias-as-C-init removes the bias MFMAs and their rounding. k-permutation
//   pi(g,j) = 4g+j (j<4) | 16+4g+(j-4) (j>=4),  g = lane>>4
// applied to BOTH A-tables and B-activations makes the D layout
// (col=lane&15, row=4*(lane>>4)+reg, m89-verified) feed the next layer's
// B slots in-lane: zero cross-lane ops.

#define NB 131072
#define DD 32
#define NL 40
#define WTAB_BYTES ((NL + 1) * 4 * 64 * 16)  // int4 [41][4 part][64 lane]
// bias table: float4 [41][2][64] right after wtab

typedef short bf16x8 __attribute__((ext_vector_type(8)));
typedef float f32x4 __attribute__((ext_vector_type(4)));

union Frag { int4 q; int i[4]; bf16x8 v; };
union BFrag { float4 q; f32x4 v; };

__device__ inline unsigned f2bf(float f) {  // fp32 -> bf16 bits, RNE
  unsigned u = __float_as_uint(f);
  return (u + 0x7fffu + ((u >> 16) & 1u)) >> 16;
}
__device__ inline float bf2f(unsigned s) { return __int_as_float((int)(s << 16)); }

// ---- table build ----------------------------------------------------------
// wtab[l][p][lane]: p=0: W[m][pi] hi, p=1: W[16+m][pi] hi, p=2/3: lo parts.
// btab[l][a][lane]: float4 bias for acc rows {16a + 4g + r}.
__global__ __launch_bounds__(64) void build_tables(
    const float* __restrict__ Wh, const float* __restrict__ bh,
    const float* __restrict__ Wout, const float* __restrict__ bout,
    int4* __restrict__ wtab, float4* __restrict__ btab) {
  const int l = blockIdx.x;      // 0..40 (40 == output layer)
  const int lane = threadIdx.x;  // 0..63
  const int m = lane & 15, g = lane >> 4;
  for (int p = 0; p < 4; ++p) {
    const int row = (p & 1) ? (16 + m) : m;
    const bool lopart = (p >= 2);
    int wds[4];
    for (int w = 0; w < 4; ++w) {
      unsigned wd = 0;
      for (int e = 0; e < 2; ++e) {
        const int j = 2 * w + e;
        const int k = (j < 4) ? (4 * g + j) : (16 + 4 * g + (j - 4));  // pi
        float v;
        if (l < NL) v = Wh[(l * 32 + row) * 32 + k];
        else        v = (row == 0) ? Wout[k] : 0.f;  // final: row0 = W_out
        unsigned hi = f2bf(v);
        unsigned val = lopart ? f2bf(v - bf2f(hi)) : hi;
        wd |= val << (16 * e);
      }
      wds[w] = (int)wd;
    }
    wtab[(l * 4 + p) * 64 + lane] = make_int4(wds[0], wds[1], wds[2], wds[3]);
  }
  for (int a = 0; a < 2; ++a) {
    float bv[4];
    for (int r = 0; r < 4; ++r) {
      const int row = 16 * a + 4 * g + r;
      bv[r] = (l < NL) ? bh[l * 32 + row] : ((row == 0) ? bout[0] : 0.f);
    }
    btab[(l * 2 + a) * 64 + lane] = make_float4(bv[0], bv[1], bv[2], bv[3]);
  }
}

// ---- main kernel ----------------------------------------------------------
__device__ inline int cvt_pk(float a, float b) {  // a -> lo16, b -> hi16
  int r;
  asm("v_cvt_pk_bf16_f32 %0, %1, %2" : "=v"(r) : "v"(a), "v"(b));
  return r;
}
__device__ inline void split2(float a, float b, int& hi, int& lo) {
  hi = cvt_pk(a, b);
  float ha = __int_as_float(hi << 16);
  float hb = __int_as_float(hi & (int)0xffff0000u);
  lo = cvt_pk(a - ha, b - hb);
}

#define MFMA16(A, B, C) __builtin_amdgcn_mfma_f32_16x16x32_bf16((A), (B), (C), 0, 0, 0)

__global__ __launch_bounds__(256, 4) void policy_mfma(
    const float* __restrict__ state, const int4* __restrict__ wtab,
    const float4* __restrict__ btab, float* __restrict__ out) {
  const int lane = threadIdx.x & 63;
  const int wid = (int)((blockIdx.x * blockDim.x + threadIdx.x) >> 6);
  const int n = lane & 15, g = lane >> 4;
  const int bbase = wid * 32;  // 32 batch cols per wave (2 x 16-col tiles)

  // Layer-0 B frags from state, pi layout: slots j<4 <- x[4g+j], j>=4 <- x[16+4g+(j-4)]
  Frag bhi[2], blo[2];
#pragma unroll
  for (int t = 0; t < 2; ++t) {
    const float* xr = state + (size_t)(bbase + 16 * t + n) * DD;
    float4 xa = *(const float4*)(xr + 4 * g);
    float4 xc = *(const float4*)(xr + 16 + 4 * g);
    split2(xa.x, xa.y, bhi[t].i[0], blo[t].i[0]);
    split2(xa.z, xa.w, bhi[t].i[1], blo[t].i[1]);
    split2(xc.x, xc.y, bhi[t].i[2], blo[t].i[2]);
    split2(xc.z, xc.w, bhi[t].i[3], blo[t].i[3]);
  }

  // prefetch layer-0 fragments (uniform stride advance)
  const int4* wp = wtab + lane;
  const float4* bp = btab + lane;
  int4 nw0h = wp[0], nw1h = wp[64], nw0l = wp[128], nw1l = wp[192];
  float4 nb0 = bp[0], nb1 = bp[64];

  float res0 = 0.f, res1 = 0.f;

#pragma unroll 1
  for (int l = 0; l <= NL; ++l) {
    Frag w0h, w1h, w0l, w1l;
    w0h.q = nw0h; w1h.q = nw1h; w0l.q = nw0l; w1l.q = nw1l;
    BFrag c0, c1;
    c0.q = nb0; c1.q = nb1;
    if (l < NL) {  // prefetch next layer
      wp += 256; bp += 128;
      nw0h = wp[0]; nw1h = wp[64]; nw0l = wp[128]; nw1l = wp[192];
      nb0 = bp[0]; nb1 = bp[64];
    }

    // 4 independent 3-deep chains (a00/a01 = tile0 rows 0-15/16-31, a1x = tile1)
    f32x4 a00 = MFMA16(w0h.v, bhi[0].v, c0.v);
    f32x4 a01 = MFMA16(w1h.v, bhi[0].v, c1.v);
    f32x4 a10 = MFMA16(w0h.v, bhi[1].v, c0.v);
    f32x4 a11 = MFMA16(w1h.v, bhi[1].v, c1.v);
    a00 = MFMA16(w0l.v, bhi[0].v, a00);
    a01 = MFMA16(w1l.v, bhi[0].v, a01);
    a10 = MFMA16(w0l.v, bhi[1].v, a10);
    a11 = MFMA16(w1l.v, bhi[1].v, a11);
    a00 = MFMA16(w0h.v, blo[0].v, a00);
    a01 = MFMA16(w1h.v, blo[0].v, a01);
    a10 = MFMA16(w0h.v, blo[1].v, a10);
    a11 = MFMA16(w1h.v, blo[1].v, a11);

    if (l < NL) {
      // relu + split; D reg r of accX0 -> slot j=r (k=4g+r), accX1 -> slot 4+r
      split2(fmaxf(a00[0], 0.f), fmaxf(a00[1], 0.f), bhi[0].i[0], blo[0].i[0]);
      split2(fmaxf(a00[2], 0.f), fmaxf(a00[3], 0.f), bhi[0].i[1], blo[0].i[1]);
      split2(fmaxf(a01[0], 0.f), fmaxf(a01[1], 0.f), bhi[0].i[2], blo[0].i[2]);
      split2(fmaxf(a01[2], 0.f), fmaxf(a01[3], 0.f), bhi[0].i[3], blo[0].i[3]);
      split2(fmaxf(a10[0], 0.f), fmaxf(a10[1], 0.f), bhi[1].i[0], blo[1].i[0]);
      split2(fmaxf(a10[2], 0.f), fmaxf(a10[3], 0.f), bhi[1].i[1], blo[1].i[1]);
      split2(fmaxf(a11[0], 0.f), fmaxf(a11[1], 0.f), bhi[1].i[2], blo[1].i[2]);
      split2(fmaxf(a11[2], 0.f), fmaxf(a11[3], 0.f), bhi[1].i[3], blo[1].i[3]);
    } else {
      res0 = a00[0];  // row 0 lives in reg 0 of lanes g==0 (lane<16)
      res1 = a10[0];
    }
  }

  if (lane < 16) {
    out[bbase + n] = res0;
    out[bbase + 16 + n] = res1;
  }
}

extern "C" void kernel_launch(void* const* d_in, const int* in_sizes, int n_in,
                              void* d_out, int out_size, void* d_ws, size_t ws_size,
                              hipStream_t stream) {
  const float* state = (const float*)d_in[0];
  const float* Wh    = (const float*)d_in[1];
  const float* bh    = (const float*)d_in[2];
  const float* Wout  = (const float*)d_in[3];
  const float* bout  = (const float*)d_in[4];
  float* out = (float*)d_out;

  int4* wtab = (int4*)d_ws;
  float4* btab = (float4*)((char*)d_ws + WTAB_BYTES);

  build_tables<<<NL + 1, 64, 0, stream>>>(Wh, bh, Wout, bout, wtab, btab);

  // 131072 rows / 32 per wave = 4096 waves; 256-thread blocks -> 1024 blocks.
  policy_mfma<<<(NB / 32) * 64 / 256, 256, 0, stream>>>(state, wtab, btab, out);
}